// Round 9
// baseline (63.953 us; speedup 1.0000x reference)
//
#include <hip/hip_runtime.h>
#include <math.h>

#define BATCH 256
#define FEAT 128
#define CAP 100000
#define ROWF 168
#define K 5
#define NBLK2 782           // blocks of 128 keys; 782*128 = 100096 >= CAP
#define NCHK 6256           // 16-key chunks; CAP%16==0 -> chunks all-real or all-pad
#define SCPT 7              // ceil(NCHK/1024)
#define MAXSEL 48
#define MARGIN 0.008f

// out layout (floats): retrieved [0,215040) | top_sims | valid_mask | top_idx
#define OUT_SIMS 215040
#define OUT_MASK 216320
#define OUT_IDX  217600

// ws layout (float units)
#define WS_QN    0          // 256*128 f32 normalized queries (exact rescore)
#define WS_QF    32768      // 4096 uint4 = bf16 B-fragments
#define WS_TMAX  49152      // 256*6256 f32 chunk maxima

typedef __attribute__((ext_vector_type(8))) short short8;
typedef __attribute__((ext_vector_type(4))) float f32x4;

#define BET(vs,vi,ss,ii) ((vs) > (ss) || ((vs) == (ss) && (vi) < (ii)))

__device__ __forceinline__ unsigned short f2bf(float f) {
  unsigned u = __float_as_uint(f);
  u += 0x7fffu + ((u >> 16) & 1u);     // RNE (proven R4-R8; margin analysis assumes RNE)
  return (unsigned short)(u >> 16);
}
__device__ __forceinline__ unsigned pack2(float a, float b) {
  return (unsigned)f2bf(a) | ((unsigned)f2bf(b) << 16);
}

// sorted-5 insert, explicit (value desc, idx asc) tie-break
__device__ __forceinline__ void ins_cmp(float v, int k, float (&s)[5], int (&i)[5]) {
  if (BET(v,k,s[4],i[4])) {
    if (BET(v,k,s[3],i[3])) { s[4]=s[3]; i[4]=i[3];
      if (BET(v,k,s[2],i[2])) { s[3]=s[2]; i[3]=i[2];
        if (BET(v,k,s[1],i[1])) { s[2]=s[1]; i[2]=i[1];
          if (BET(v,k,s[0],i[0])) { s[1]=s[0]; i[1]=i[0]; s[0]=v; i[0]=k; }
          else { s[1]=v; i[1]=k; } }
        else { s[2]=v; i[2]=k; } }
      else { s[3]=v; i[3]=k; } }
    else { s[4]=v; i[4]=k; }
  }
}

// grid 16 (q-groups of 16), block 256. Writes f32 qn + bf16 B-fragments.
__global__ __launch_bounds__(256) void prep_q(const float* __restrict__ q,
                                              float* __restrict__ qn,
                                              uint4* __restrict__ qF) {
  int tid = threadIdx.x, qg = blockIdx.x;
  int qi = tid >> 4;             // query in group (0..15)
  int d0 = (tid & 15) * 8;
  int q_ = qg*16 + qi;
  const float4* src = reinterpret_cast<const float4*>(q + (size_t)q_*FEAT + d0);
  float4 v0 = src[0], v1 = src[1];
  float ss = v0.x*v0.x + v0.y*v0.y + v0.z*v0.z + v0.w*v0.w
           + v1.x*v1.x + v1.y*v1.y + v1.z*v1.z + v1.w*v1.w;
  ss += __shfl_xor(ss,1); ss += __shfl_xor(ss,2);
  ss += __shfl_xor(ss,4); ss += __shfl_xor(ss,8);
  float inv = 1.0f / fmaxf(sqrtf(ss), 1e-12f);
  v0.x*=inv; v0.y*=inv; v0.z*=inv; v0.w*=inv;
  v1.x*=inv; v1.y*=inv; v1.z*=inv; v1.w*=inv;
  float4* dst = reinterpret_cast<float4*>(qn + (size_t)q_*FEAT + d0);
  dst[0] = v0; dst[1] = v1;
  uint4 pk;
  pk.x = pack2(v0.x,v0.y); pk.y = pack2(v0.z,v0.w);
  pk.z = pack2(v1.x,v1.y); pk.w = pack2(v1.z,v1.w);
  int s_ = d0 >> 5, lg = (d0 >> 3) & 3;
  qF[((qg*4 + s_)*64) + lg*16 + qi] = pk;
}

// grid NBLK2 (128 keys/block), block 512 (8 waves; wave w owns q-groups 2w,2w+1).
// ALL staging loads hoisted up front (8 float4 + 4 ts in flight per thread ->
// HBM latency covered), then scale+pack to LDS A-frag slabs, MFMA, tile maxima.
__global__ __launch_bounds__(512, 4) void gemm_max(
    const float* __restrict__ keys, const int* __restrict__ ts,
    const int* __restrict__ gstep, const uint4* __restrict__ qF,
    float* __restrict__ tmax) {
  __shared__ uint4 lds_kf[32*66];      // 8 tiles x 4 slabs, stride 66 (33 KB)
  int tid = threadIdx.x;
  int w = tid >> 6, lane = tid & 63;
  int blk = blockIdx.x;
  int kbase = blk * 128;
  int gstep0 = gstep[0];

  // issue query-fragment loads (L2 broadcast) early
  short8 qf0[4], qf1[4];
  #pragma unroll
  for (int s_ = 0; s_ < 4; ++s_) {
    qf0[s_] = __builtin_bit_cast(short8, qF[((2*w  )*4 + s_)*64 + lane]);
    qf1[s_] = __builtin_bit_cast(short8, qF[((2*w+1)*4 + s_)*64 + lane]);
  }

  // hoisted staging loads: 8 x dwordx4 + 4 ts, no dependent math between
  float4 va[4][2];
  int tsv[4];
  int dp = tid & 15;                   // 8-dim slice
  #pragma unroll
  for (int it = 0; it < 4; ++it) {
    int gk = kbase + it*32 + (tid >> 4);
    float4 z = {0,0,0,0};
    va[it][0] = z; va[it][1] = z; tsv[it] = gstep0;
    if (gk < CAP) {
      const float4* kp = reinterpret_cast<const float4*>(keys + (size_t)gk*FEAT + dp*8);
      va[it][0] = kp[0]; va[it][1] = kp[1];
      tsv[it] = ts[gk];
    }
  }

  // process: norm-reduce, scale, pack, LDS write (loads already in flight)
  #pragma unroll
  for (int it = 0; it < 4; ++it) {
    int kl = it*32 + (tid >> 4);
    int gk = kbase + kl;
    float4 v0 = va[it][0], v1 = va[it][1];
    float ss = v0.x*v0.x+v0.y*v0.y+v0.z*v0.z+v0.w*v0.w
             + v1.x*v1.x+v1.y*v1.y+v1.z*v1.z+v1.w*v1.w;
    ss += __shfl_xor(ss,1); ss += __shfl_xor(ss,2);
    ss += __shfl_xor(ss,4); ss += __shfl_xor(ss,8);
    float scl = 0.0f;
    if (gk < CAP) {
      float age = (float)(gstep0 - tsv[it]);
      scl = exp2f(age * -0.00723157f) / fmaxf(sqrtf(ss), 1e-12f);  // approx only
    }
    uint4 pk;
    pk.x = pack2(v0.x*scl, v0.y*scl); pk.y = pack2(v0.z*scl, v0.w*scl);
    pk.z = pack2(v1.x*scl, v1.y*scl); pk.w = pack2(v1.z*scl, v1.w*scl);
    int slab = (kl >> 4)*4 + (dp >> 2);
    int slot = (dp & 3)*16 + (kl & 15);
    lds_kf[slab*66 + slot] = pk;
  }
  __syncthreads();

  float tm0[8], tm1[8];

  #pragma unroll
  for (int t = 0; t < 8; ++t) {
    f32x4 acc0 = {0.f,0.f,0.f,0.f}, acc1 = {0.f,0.f,0.f,0.f};
    #pragma unroll
    for (int s_ = 0; s_ < 4; ++s_) {
      short8 a = __builtin_bit_cast(short8, lds_kf[(t*4 + s_)*66 + lane]);
      acc0 = __builtin_amdgcn_mfma_f32_16x16x32_bf16(a, qf0[s_], acc0, 0,0,0);
      acc1 = __builtin_amdgcn_mfma_f32_16x16x32_bf16(a, qf1[s_], acc1, 0,0,0);
    }
    // C/D: col=lane&15 (query), row=(lane>>4)*4+r (key). Pad tiles give 0s
    // (scl=0), never above threshold; CAP%16==0 so no partial tiles.
    float m0 = fmaxf(fmaxf(acc0[0],acc0[1]), fmaxf(acc0[2],acc0[3]));
    float m1 = fmaxf(fmaxf(acc1[0],acc1[1]), fmaxf(acc1[2],acc1[3]));
    m0 = fmaxf(m0, __shfl_xor(m0,16)); m0 = fmaxf(m0, __shfl_xor(m0,32));
    m1 = fmaxf(m1, __shfl_xor(m1,16)); m1 = fmaxf(m1, __shfl_xor(m1,32));
    tm0[t] = m0; tm1[t] = m1;
  }

  if (lane < 16) {
    int q0 = w*32 + lane, q1 = q0 + 16;
    float4 a0 = {tm0[0],tm0[1],tm0[2],tm0[3]};
    float4 a1 = {tm0[4],tm0[5],tm0[6],tm0[7]};
    float4 b0 = {tm1[0],tm1[1],tm1[2],tm1[3]};
    float4 b1 = {tm1[4],tm1[5],tm1[6],tm1[7]};
    float4* p0 = reinterpret_cast<float4*>(&tmax[(size_t)q0*NCHK + blk*8]);
    float4* p1 = reinterpret_cast<float4*>(&tmax[(size_t)q1*NCHK + blk*8]);
    p0[0] = a0; p0[1] = a1;
    p1[0] = b0; p1[1] = b1;
  }
}

// grid 256 (1/query), block 1024 (16 waves). Single-pass hierarchical top-5
// for both the chunk-max scan and the final rescored top-5 (2 syncs each).
__global__ __launch_bounds__(1024) void select_rescore(
    const float* __restrict__ tmax, const float* __restrict__ keys,
    const float* __restrict__ qn, const int* __restrict__ ts,
    const int* __restrict__ gstep, const float* __restrict__ values,
    float* __restrict__ out) {
  int q = blockIdx.x, tid = threadIdx.x;
  int w = tid >> 6, lane = tid & 63;
  int gstep0 = gstep[0];

  __shared__ float qrow[FEAT];
  if (tid < 32)
    reinterpret_cast<float4*>(qrow)[tid] =
        reinterpret_cast<const float4*>(qn + (size_t)q*FEAT)[tid];

  // phase 1: per-thread sorted-5 of chunk maxima
  float cs[SCPT]; int ci[SCPT];
  float s5[5] = {-INFINITY,-INFINITY,-INFINITY,-INFINITY,-INFINITY};
  int   i5[5] = {0x7fffffff,0x7fffffff,0x7fffffff,0x7fffffff,0x7fffffff};
  #pragma unroll
  for (int j = 0; j < SCPT; ++j) {
    int c = tid + j*1024;
    if (c < NCHK) { cs[j] = tmax[(size_t)q*NCHK + c]; ci[j] = c; }
    else { cs[j] = -INFINITY; ci[j] = 0x7fffffff; }
    ins_cmp(cs[j], ci[j], s5, i5);
  }
  // wave merge (every lane ends with wave top-5)
  #pragma unroll
  for (int off = 1; off < 64; off <<= 1) {
    float ps[5]; int pi[5];
    #pragma unroll
    for (int j=0;j<5;++j){ ps[j]=__shfl_xor(s5[j],off); pi[j]=__shfl_xor(i5[j],off); }
    #pragma unroll
    for (int j=0;j<5;++j) ins_cmp(ps[j], pi[j], s5, i5);
  }
  __shared__ float rS[16][5]; __shared__ int rI[16][5];
  if (lane == 0) {
    #pragma unroll
    for (int j=0;j<5;++j){ rS[w][j]=s5[j]; rI[w][j]=i5[j]; }
  }
  __syncthreads();
  __shared__ float thSh;
  if (tid == 0) {
    float fs[5]; int fi[5];
    #pragma unroll
    for (int j=0;j<5;++j){ fs[j]=rS[0][j]; fi[j]=rI[0][j]; }
    for (int ww = 1; ww < 16; ++ww)
      #pragma unroll
      for (int j=0;j<5;++j) ins_cmp(rS[ww][j], rI[ww][j], fs, fi);
    thSh = fs[4] - MARGIN;     // m5a - margin
  }
  __syncthreads();
  float th = thSh;

  // phase 2: select chunks within margin
  __shared__ int cnt; __shared__ int clist[MAXSEL];
  if (tid == 0) cnt = 0;
  __syncthreads();
  #pragma unroll
  for (int j = 0; j < SCPT; ++j)
    if (cs[j] >= th && ci[j] < NCHK) {
      int p = atomicAdd(&cnt, 1);
      if (p < MAXSEL) clist[p] = ci[j];
    }
  __syncthreads();
  int nsel = cnt < MAXSEL ? cnt : MAXSEL;

  // phase 3: exact f32 rescore, 4 threads/key (wave reads 16 consecutive
  // keys = 8 KB contiguous). Reference arithmetic.
  __shared__ float exs[MAXSEL*16];
  for (int s4 = tid; s4 < nsel*64; s4 += 1024) {
    int slot = s4 >> 2, part = s4 & 3;
    int key = clist[slot >> 4]*16 + (slot & 15);
    float dot = 0.f, ksq = 0.f;
    if (key < CAP) {
      const float4* kp = reinterpret_cast<const float4*>(keys + (size_t)key*FEAT + part*32);
      const float4* qp = reinterpret_cast<float4*>(qrow) + part*8;
      #pragma unroll
      for (int d = 0; d < 8; ++d) {
        float4 kv = kp[d];
        float4 qv = qp[d];
        dot = fmaf(kv.w,qv.w,fmaf(kv.z,qv.z,fmaf(kv.y,qv.y,fmaf(kv.x,qv.x,dot))));
        ksq = fmaf(kv.w,kv.w,fmaf(kv.z,kv.z,fmaf(kv.y,kv.y,fmaf(kv.x,kv.x,ksq))));
      }
    }
    dot += __shfl_xor(dot,1); dot += __shfl_xor(dot,2);
    ksq += __shfl_xor(ksq,1); ksq += __shfl_xor(ksq,2);
    if (part == 0) {
      float sim = -INFINITY;
      if (key < CAP) {
        float age = (float)(gstep0 - ts[key]);
        sim = dot / fmaxf(sqrtf(ksq), 1e-12f) * powf(0.995f, age);
      }
      exs[slot] = sim;
    }
  }
  __syncthreads();

  // phase 4: single-pass exact top-5 of rescored candidates
  float fs5[5] = {-INFINITY,-INFINITY,-INFINITY,-INFINITY,-INFINITY};
  int   fi5[5] = {0x7fffffff,0x7fffffff,0x7fffffff,0x7fffffff,0x7fffffff};
  if (tid < nsel*16) {
    fs5[0] = exs[tid];
    fi5[0] = clist[tid >> 4]*16 + (tid & 15);
  }
  #pragma unroll
  for (int off = 1; off < 64; off <<= 1) {
    float ps[5]; int pi[5];
    #pragma unroll
    for (int j=0;j<5;++j){ ps[j]=__shfl_xor(fs5[j],off); pi[j]=__shfl_xor(fi5[j],off); }
    #pragma unroll
    for (int j=0;j<5;++j) ins_cmp(ps[j], pi[j], fs5, fi5);
  }
  if (lane == 0) {
    #pragma unroll
    for (int j=0;j<5;++j){ rS[w][j]=fs5[j]; rI[w][j]=fi5[j]; }
  }
  __syncthreads();
  __shared__ int wix[K];
  if (tid == 0) {
    float fs[5]; int fi[5];
    #pragma unroll
    for (int j=0;j<5;++j){ fs[j]=rS[0][j]; fi[j]=rI[0][j]; }
    for (int ww = 1; ww < 16; ++ww)
      #pragma unroll
      for (int j=0;j<5;++j) ins_cmp(rS[ww][j], rI[ww][j], fs, fi);
    #pragma unroll
    for (int r = 0; r < K; ++r) {
      out[OUT_SIMS + q*K + r] = fs[r];
      out[OUT_MASK + q*K + r] = (fs[r] >= 0.0f) ? 1.0f : 0.0f;
      out[OUT_IDX  + q*K + r] = (float)fi[r];
      wix[r] = fi[r];
    }
  }
  __syncthreads();
  for (int idx = tid; idx < K*ROWF; idx += 1024) {
    int r = idx / ROWF, e = idx - r*ROWF;
    out[(q*K + r)*ROWF + e] = values[(size_t)wix[r]*ROWF + e];
  }
}

extern "C" void kernel_launch(void* const* d_in, const int* in_sizes, int n_in,
                              void* d_out, int out_size, void* d_ws, size_t ws_size,
                              hipStream_t stream) {
  const float* query  = (const float*)d_in[0];
  const float* keys   = (const float*)d_in[1];
  const float* values = (const float*)d_in[2];
  const int*   ts     = (const int*)d_in[3];
  const int*   gstep  = (const int*)d_in[4];

  float* out  = (float*)d_out;
  float* wsf  = (float*)d_ws;

  float* qn   = wsf + WS_QN;
  uint4* qF   = (uint4*)(wsf + WS_QF);
  float* tmax = wsf + WS_TMAX;

  prep_q<<<16, 256, 0, stream>>>(query, qn, qF);
  gemm_max<<<NBLK2, 512, 0, stream>>>(keys, ts, gstep, qF, tmax);
  select_rescore<<<BATCH, 1024, 0, stream>>>(tmax, keys, qn, ts, gstep, values, out);
}

// Round 10
// 63.031 us; speedup vs baseline: 1.0146x; 1.0146x over previous
//
#include <hip/hip_runtime.h>
#include <math.h>

#define BATCH 256
#define FEAT 128
#define CAP 100000
#define ROWF 168
#define K 5
#define NBLK2 782           // blocks of 128 keys; 782*128 = 100096 >= CAP
#define NCHK 6256           // 16-key chunks; CAP%16==0 -> chunks all-real or all-pad
#define SCPT 13             // ceil(NCHK/512)
#define MAXSEL 48
#define MARGIN 0.008f

// out layout (floats): retrieved [0,215040) | top_sims | valid_mask | top_idx
#define OUT_SIMS 215040
#define OUT_MASK 216320
#define OUT_IDX  217600

// ws layout (float units)
#define WS_TMAX  0          // 256*6256 f32 chunk maxima

typedef __attribute__((ext_vector_type(8))) short short8;
typedef __attribute__((ext_vector_type(4))) float f32x4;

#define BET(vs,vi,ss,ii) ((vs) > (ss) || ((vs) == (ss) && (vi) < (ii)))

__device__ __forceinline__ unsigned short f2bf(float f) {
  unsigned u = __float_as_uint(f);
  u += 0x7fffu + ((u >> 16) & 1u);     // RNE (proven R4-R9)
  return (unsigned short)(u >> 16);
}
__device__ __forceinline__ unsigned pack2(float a, float b) {
  return (unsigned)f2bf(a) | ((unsigned)f2bf(b) << 16);
}

// sorted-5 insert, explicit (value desc, idx asc) tie-break
__device__ __forceinline__ void ins_cmp(float v, int k, float (&s)[5], int (&i)[5]) {
  if (BET(v,k,s[4],i[4])) {
    if (BET(v,k,s[3],i[3])) { s[4]=s[3]; i[4]=i[3];
      if (BET(v,k,s[2],i[2])) { s[3]=s[2]; i[3]=i[2];
        if (BET(v,k,s[1],i[1])) { s[2]=s[1]; i[2]=i[1];
          if (BET(v,k,s[0],i[0])) { s[1]=s[0]; i[1]=i[0]; s[0]=v; i[0]=k; }
          else { s[1]=v; i[1]=k; } }
        else { s[2]=v; i[2]=k; } }
      else { s[3]=v; i[3]=k; } }
    else { s[4]=v; i[4]=k; }
  }
}

// grid NBLK2 (128 keys/block), block 512 (8 waves; wave w owns q-groups 2w,2w+1).
// Self-contained: computes bf16 query fragments in-block (2 LDS passes,
// bit-identical to the old prep_q math), then stages 128 scaled bf16 keys
// into LDS A-frag slabs (stride 66), MFMA, emits per-16-key-tile maxima.
__global__ __launch_bounds__(512, 4) void gemm_max2(
    const float* __restrict__ keys, const int* __restrict__ ts,
    const int* __restrict__ gstep, const float* __restrict__ query,
    float* __restrict__ tmax) {
  __shared__ uint4 lds_kf[32*66];      // 33 KB; reused: qF staging then key slabs
  int tid = threadIdx.x;
  int w = tid >> 6, lane = tid & 63;
  int blk = blockIdx.x;
  int kbase = blk * 128;
  int gstep0 = gstep[0];

  // ---- embedded prep_q: two passes of 8 query-groups through LDS ----
  short8 qf0[4], qf1[4];
  #pragma unroll
  for (int p = 0; p < 2; ++p) {
    #pragma unroll
    for (int j = 0; j < 4; ++j) {
      int q_ = p*128 + j*32 + (tid >> 4);   // query row
      int d0 = (tid & 15) * 8;
      const float4* src = reinterpret_cast<const float4*>(query + (size_t)q_*FEAT + d0);
      float4 v0 = src[0], v1 = src[1];
      float ss = v0.x*v0.x + v0.y*v0.y + v0.z*v0.z + v0.w*v0.w
               + v1.x*v1.x + v1.y*v1.y + v1.z*v1.z + v1.w*v1.w;
      ss += __shfl_xor(ss,1); ss += __shfl_xor(ss,2);
      ss += __shfl_xor(ss,4); ss += __shfl_xor(ss,8);
      float inv = 1.0f / fmaxf(sqrtf(ss), 1e-12f);
      v0.x*=inv; v0.y*=inv; v0.z*=inv; v0.w*=inv;
      v1.x*=inv; v1.y*=inv; v1.z*=inv; v1.w*=inv;
      uint4 pk;
      pk.x = pack2(v0.x,v0.y); pk.y = pack2(v0.z,v0.w);
      pk.z = pack2(v1.x,v1.y); pk.w = pack2(v1.z,v1.w);
      int qgl = (q_ >> 4) - p*8;            // local group 0..7
      int qi = q_ & 15, s_ = d0 >> 5, lg = (d0 >> 3) & 3;
      lds_kf[(qgl*4 + s_)*64 + lg*16 + qi] = pk;
    }
    __syncthreads();
    if ((w >> 2) == p) {                    // waves 0-3 take pass 0, 4-7 pass 1
      int gl = 2*(w - 4*p);
      #pragma unroll
      for (int s_ = 0; s_ < 4; ++s_) {
        qf0[s_] = __builtin_bit_cast(short8, lds_kf[((gl  )*4 + s_)*64 + lane]);
        qf1[s_] = __builtin_bit_cast(short8, lds_kf[((gl+1)*4 + s_)*64 + lane]);
      }
    }
    __syncthreads();
  }

  // ---- key staging (R8 form: interleaved load/process, no hoist) ----
  #pragma unroll
  for (int it = 0; it < 4; ++it) {
    int kl = it*32 + (tid >> 4);       // local key 0..127
    int dp = tid & 15;                 // 8-dim slice
    int gk = kbase + kl;
    float4 v0 = {0,0,0,0}, v1 = {0,0,0,0};
    if (gk < CAP) {
      const float4* kp = reinterpret_cast<const float4*>(keys + (size_t)gk*FEAT + dp*8);
      v0 = kp[0]; v1 = kp[1];
    }
    float ss = v0.x*v0.x+v0.y*v0.y+v0.z*v0.z+v0.w*v0.w
             + v1.x*v1.x+v1.y*v1.y+v1.z*v1.z+v1.w*v1.w;
    ss += __shfl_xor(ss,1); ss += __shfl_xor(ss,2);
    ss += __shfl_xor(ss,4); ss += __shfl_xor(ss,8);
    float scl = 0.0f;
    if (gk < CAP) {
      float age = (float)(gstep0 - ts[gk]);
      scl = exp2f(age * -0.00723157f) / fmaxf(sqrtf(ss), 1e-12f);  // approx only
    }
    uint4 pk;
    pk.x = pack2(v0.x*scl, v0.y*scl); pk.y = pack2(v0.z*scl, v0.w*scl);
    pk.z = pack2(v1.x*scl, v1.y*scl); pk.w = pack2(v1.z*scl, v1.w*scl);
    int slab = (kl >> 4)*4 + (dp >> 2);
    int slot = (dp & 3)*16 + (kl & 15);
    lds_kf[slab*66 + slot] = pk;
  }
  __syncthreads();

  float tm0[8], tm1[8];
  #pragma unroll
  for (int t = 0; t < 8; ++t) {
    f32x4 acc0 = {0.f,0.f,0.f,0.f}, acc1 = {0.f,0.f,0.f,0.f};
    #pragma unroll
    for (int s_ = 0; s_ < 4; ++s_) {
      short8 a = __builtin_bit_cast(short8, lds_kf[(t*4 + s_)*66 + lane]);
      acc0 = __builtin_amdgcn_mfma_f32_16x16x32_bf16(a, qf0[s_], acc0, 0,0,0);
      acc1 = __builtin_amdgcn_mfma_f32_16x16x32_bf16(a, qf1[s_], acc1, 0,0,0);
    }
    // C/D: col=lane&15 (query), row=(lane>>4)*4+r (key). Pad keys have scl=0
    // -> sims 0; CAP%16==0 so tiles are all-real or all-pad.
    float m0 = fmaxf(fmaxf(acc0[0],acc0[1]), fmaxf(acc0[2],acc0[3]));
    float m1 = fmaxf(fmaxf(acc1[0],acc1[1]), fmaxf(acc1[2],acc1[3]));
    m0 = fmaxf(m0, __shfl_xor(m0,16)); m0 = fmaxf(m0, __shfl_xor(m0,32));
    m1 = fmaxf(m1, __shfl_xor(m1,16)); m1 = fmaxf(m1, __shfl_xor(m1,32));
    tm0[t] = m0; tm1[t] = m1;
  }

  if (lane < 16) {
    int q0 = w*32 + lane, q1 = q0 + 16;
    float4 a0 = {tm0[0],tm0[1],tm0[2],tm0[3]};
    float4 a1 = {tm0[4],tm0[5],tm0[6],tm0[7]};
    float4 b0 = {tm1[0],tm1[1],tm1[2],tm1[3]};
    float4 b1 = {tm1[4],tm1[5],tm1[6],tm1[7]};
    float4* p0 = reinterpret_cast<float4*>(&tmax[(size_t)q0*NCHK + blk*8]);
    float4* p1 = reinterpret_cast<float4*>(&tmax[(size_t)q1*NCHK + blk*8]);
    p0[0] = a0; p0[1] = a1;
    p1[0] = b0; p1[1] = b1;
  }
}

// grid 256 (1/query), block 512 (8 waves). Normalizes its own query row
// (bit-identical to old prep_q math), then: m5a over chunk maxima -> select
// chunks >= m5a - MARGIN -> exact f32 rescore -> exact top-5 + gather.
__global__ __launch_bounds__(512) void select_rescore2(
    const float* __restrict__ tmax, const float* __restrict__ keys,
    const float* __restrict__ query, const int* __restrict__ ts,
    const int* __restrict__ gstep, const float* __restrict__ values,
    float* __restrict__ out) {
  int q = blockIdx.x, tid = threadIdx.x;
  int w = tid >> 6, lane = tid & 63;
  int gstep0 = gstep[0];

  // normalize own query row: 16 threads x 8 dims, prep_q's exact op order
  __shared__ float qrow[FEAT];
  if (tid < 16) {
    int d0 = tid * 8;
    const float4* src = reinterpret_cast<const float4*>(query + (size_t)q*FEAT + d0);
    float4 v0 = src[0], v1 = src[1];
    float ss = v0.x*v0.x + v0.y*v0.y + v0.z*v0.z + v0.w*v0.w
             + v1.x*v1.x + v1.y*v1.y + v1.z*v1.z + v1.w*v1.w;
    ss += __shfl_xor(ss,1); ss += __shfl_xor(ss,2);
    ss += __shfl_xor(ss,4); ss += __shfl_xor(ss,8);
    float inv = 1.0f / fmaxf(sqrtf(ss), 1e-12f);
    v0.x*=inv; v0.y*=inv; v0.z*=inv; v0.w*=inv;
    v1.x*=inv; v1.y*=inv; v1.z*=inv; v1.w*=inv;
    float4* dst = reinterpret_cast<float4*>(qrow + d0);
    dst[0] = v0; dst[1] = v1;
  }
  __syncthreads();

  // phase 1: per-thread sorted-5 of chunk maxima, then wave + block merge
  float cs[SCPT]; int ci[SCPT];
  float s5[5] = {-INFINITY,-INFINITY,-INFINITY,-INFINITY,-INFINITY};
  int   i5[5] = {0x7fffffff,0x7fffffff,0x7fffffff,0x7fffffff,0x7fffffff};
  #pragma unroll
  for (int j = 0; j < SCPT; ++j) {
    int c = tid + j*512;
    if (c < NCHK) { cs[j] = tmax[(size_t)q*NCHK + c]; ci[j] = c; }
    else { cs[j] = -INFINITY; ci[j] = 0x7fffffff; }
    ins_cmp(cs[j], ci[j], s5, i5);
  }
  #pragma unroll
  for (int off = 1; off < 64; off <<= 1) {
    float ps[5]; int pi[5];
    #pragma unroll
    for (int j=0;j<5;++j){ ps[j]=__shfl_xor(s5[j],off); pi[j]=__shfl_xor(i5[j],off); }
    #pragma unroll
    for (int j=0;j<5;++j) ins_cmp(ps[j], pi[j], s5, i5);
  }
  __shared__ float rS[8][5]; __shared__ int rI[8][5];
  if (lane == 0) {
    #pragma unroll
    for (int j=0;j<5;++j){ rS[w][j]=s5[j]; rI[w][j]=i5[j]; }
  }
  __syncthreads();
  __shared__ float thSh;
  if (tid == 0) {
    float fs[5]; int fi[5];
    #pragma unroll
    for (int j=0;j<5;++j){ fs[j]=rS[0][j]; fi[j]=rI[0][j]; }
    for (int ww = 1; ww < 8; ++ww)
      #pragma unroll
      for (int j=0;j<5;++j) ins_cmp(rS[ww][j], rI[ww][j], fs, fi);
    thSh = fs[4] - MARGIN;     // m5a - margin
  }
  __syncthreads();
  float th = thSh;

  // phase 2: select chunks within margin
  __shared__ int cnt; __shared__ int clist[MAXSEL];
  if (tid == 0) cnt = 0;
  __syncthreads();
  #pragma unroll
  for (int j = 0; j < SCPT; ++j)
    if (cs[j] >= th && ci[j] < NCHK) {
      int p = atomicAdd(&cnt, 1);
      if (p < MAXSEL) clist[p] = ci[j];
    }
  __syncthreads();
  int nsel = cnt < MAXSEL ? cnt : MAXSEL;

  // phase 3: exact f32 rescore, 4 threads/key (wave = 16 consecutive keys)
  __shared__ float exs[MAXSEL*16];
  for (int s4 = tid; s4 < nsel*64; s4 += 512) {
    int slot = s4 >> 2, part = s4 & 3;
    int key = clist[slot >> 4]*16 + (slot & 15);
    float dot = 0.f, ksq = 0.f;
    if (key < CAP) {
      const float4* kp = reinterpret_cast<const float4*>(keys + (size_t)key*FEAT + part*32);
      const float4* qp = reinterpret_cast<float4*>(qrow) + part*8;
      #pragma unroll
      for (int d = 0; d < 8; ++d) {
        float4 kv = kp[d];
        float4 qv = qp[d];
        dot = fmaf(kv.w,qv.w,fmaf(kv.z,qv.z,fmaf(kv.y,qv.y,fmaf(kv.x,qv.x,dot))));
        ksq = fmaf(kv.w,kv.w,fmaf(kv.z,kv.z,fmaf(kv.y,kv.y,fmaf(kv.x,kv.x,ksq))));
      }
    }
    dot += __shfl_xor(dot,1); dot += __shfl_xor(dot,2);
    ksq += __shfl_xor(ksq,1); ksq += __shfl_xor(ksq,2);
    if (part == 0) {
      float sim = -INFINITY;
      if (key < CAP) {
        float age = (float)(gstep0 - ts[key]);
        sim = dot / fmaxf(sqrtf(ksq), 1e-12f) * powf(0.995f, age);
      }
      exs[slot] = sim;
    }
  }
  __syncthreads();

  // phase 4: single-pass exact top-5 of rescored candidates
  float fs5[5] = {-INFINITY,-INFINITY,-INFINITY,-INFINITY,-INFINITY};
  int   fi5[5] = {0x7fffffff,0x7fffffff,0x7fffffff,0x7fffffff,0x7fffffff};
  if (tid < nsel*16) {
    fs5[0] = exs[tid];
    fi5[0] = clist[tid >> 4]*16 + (tid & 15);
  }
  #pragma unroll
  for (int off = 1; off < 64; off <<= 1) {
    float ps[5]; int pi[5];
    #pragma unroll
    for (int j=0;j<5;++j){ ps[j]=__shfl_xor(fs5[j],off); pi[j]=__shfl_xor(fi5[j],off); }
    #pragma unroll
    for (int j=0;j<5;++j) ins_cmp(ps[j], pi[j], fs5, fi5);
  }
  if (lane == 0) {
    #pragma unroll
    for (int j=0;j<5;++j){ rS[w][j]=fs5[j]; rI[w][j]=fi5[j]; }
  }
  __syncthreads();
  __shared__ int wix[K];
  if (tid == 0) {
    float fs[5]; int fi[5];
    #pragma unroll
    for (int j=0;j<5;++j){ fs[j]=rS[0][j]; fi[j]=rI[0][j]; }
    for (int ww = 1; ww < 8; ++ww)
      #pragma unroll
      for (int j=0;j<5;++j) ins_cmp(rS[ww][j], rI[ww][j], fs, fi);
    #pragma unroll
    for (int r = 0; r < K; ++r) {
      out[OUT_SIMS + q*K + r] = fs[r];
      out[OUT_MASK + q*K + r] = (fs[r] >= 0.0f) ? 1.0f : 0.0f;
      out[OUT_IDX  + q*K + r] = (float)fi[r];
      wix[r] = fi[r];
    }
  }
  __syncthreads();
  for (int idx = tid; idx < K*ROWF; idx += 512) {
    int r = idx / ROWF, e = idx - r*ROWF;
    out[(q*K + r)*ROWF + e] = values[(size_t)wix[r]*ROWF + e];
  }
}

extern "C" void kernel_launch(void* const* d_in, const int* in_sizes, int n_in,
                              void* d_out, int out_size, void* d_ws, size_t ws_size,
                              hipStream_t stream) {
  const float* query  = (const float*)d_in[0];
  const float* keys   = (const float*)d_in[1];
  const float* values = (const float*)d_in[2];
  const int*   ts     = (const int*)d_in[3];
  const int*   gstep  = (const int*)d_in[4];

  float* out  = (float*)d_out;
  float* wsf  = (float*)d_ws;
  float* tmax = wsf + WS_TMAX;

  gemm_max2<<<NBLK2, 512, 0, stream>>>(keys, ts, gstep, query, tmax);
  select_rescore2<<<BATCH, 512, 0, stream>>>(tmax, keys, query, ts, gstep, values, out);
}